// Round 6
// baseline (458.086 us; speedup 1.0000x reference)
//
#include <hip/hip_runtime.h>
#include <hip/hip_bf16.h>

// GraphSAGE (GCN-aggregator) — 3 layers, fp32.
// Structure: transform-then-aggregate ((seg(t)+t)*inv + b, t = h@W^T).
// R6 changes (fill_from_bins was 71.6us, WRITE 68.6MB, 12.5% lane util):
//  (a) plane-split ELL [4][N][16]: slot s -> plane s>>4, 64B line per
//      (plane,node). ~89% of edges land in plane 0 => hot region/bucket
//      0.8MB (L2-resident), writes line-dense.
//  (b) fill processes 8 bin-segments/wave (lane = sub-seg x record, 3
//      tiers, ballot early-out): lane util 12.5% -> ~60%.
//  (c) nontemporal bins/cnt traffic (read-once) to stop L2 thrash.
// fp32 throughout (bf16 would exceed the 7.1e-4 absmax threshold).

#define N_FEAT 64
#define CAP 64    // ELL slots per node (4 planes of 16)
#define CAPW 24   // bin slots per (bucket, wave): Binom(64,1/8) mean 8
#define OVF_CAP 4096

// ---- phase 1: bin edges by dst bucket (atomic-free, wave-aggregated) ----
__global__ __launch_bounds__(256) void bin_edges(const int* __restrict__ src,
                                                 const int* __restrict__ dst,
                                                 unsigned int* __restrict__ bins,  // [8, nw, CAPW]
                                                 int* __restrict__ cnt,            // [nw, 8]
                                                 int* __restrict__ ovf,            // [OVF_CAP*2]
                                                 int* __restrict__ ovf_cnt,
                                                 int n_edges, int bsize, int nw) {
    const int e = blockIdx.x * 256 + threadIdx.x;
    const int lane = threadIdx.x & 63;
    const int wid = (blockIdx.x << 2) | (threadIdx.x >> 6);
    const bool valid = e < n_edges;
    int s = 0, d = 0;
    if (valid) { s = src[e]; d = dst[e]; }
    const unsigned int bucket = valid ? ((unsigned int)d / (unsigned int)bsize) : 8u;
    const unsigned int local = valid ? (unsigned int)(d - (int)bucket * bsize) : 0u;
    const unsigned int pack = (local << 17) | (unsigned int)s;

    int mycnt = 0;
    for (int c = 0; c < 8; ++c) {
        unsigned long long m = __ballot(valid && bucket == (unsigned int)c);
        int cc = __popcll(m);
        if (lane == c) mycnt = (cc < CAPW) ? cc : CAPW;
        if (valid && bucket == (unsigned int)c) {
            int pfx = __popcll(m & ((1ull << lane) - 1ull));
            if (pfx < CAPW) {
                __builtin_nontemporal_store(pack, &bins[((size_t)c * nw + wid) * CAPW + pfx]);
            } else {
                int p = atomicAdd(ovf_cnt, 1);
                if (p < OVF_CAP) { ovf[2 * p] = s; ovf[2 * p + 1] = d; }
            }
        }
    }
    if (lane < 8) __builtin_nontemporal_store(mycnt, &cnt[wid * 8 + lane]);
}

// ---- phase 2: scatter bins into plane-split ELL; bucket = blockIdx%8 ----
__global__ __launch_bounds__(256) void fill_from_bins(const unsigned int* __restrict__ bins,
                                                      const int* __restrict__ cnt,
                                                      const int* __restrict__ ovf,
                                                      const int* __restrict__ ovf_cnt,
                                                      int* __restrict__ deg,
                                                      int* __restrict__ ell,
                                                      int nw, int bsize, int n_nodes) {
    const int lane = threadIdx.x & 63;
    const int w = threadIdx.x >> 6;
    const int c = blockIdx.x & 7;          // bucket -> XCD (round-robin dispatch)
    const int jb = blockIdx.x >> 3;
    const int base_node = c * bsize;
    const int sub = lane >> 3;             // 8 sub-segments per wave
    const int rr = lane & 7;               // record id within tier
    const int wave_in_bucket = jb * 4 + w;
    const int nwaves = (gridDim.x >> 3) * 4;

    for (int s0 = wave_in_bucket * 8; s0 < nw; s0 += nwaves * 8) {
        const int sg = s0 + sub;
        const int n = (sg < nw) ? __builtin_nontemporal_load(&cnt[sg * 8 + c]) : 0;
#pragma unroll
        for (int t = 0; t < 3; ++t) {          // tiers: records 0-7, 8-15, 16-23
            const int rec = t * 8 + rr;
            const bool act = rec < n;
            unsigned long long bm = __ballot(act);
            if (!bm) break;                    // wave-uniform early out
            if (act) {
                unsigned int v = __builtin_nontemporal_load(
                    &bins[((size_t)c * nw + sg) * CAPW + rec]);
                int sv = (int)(v & 0x1FFFFu);
                int d = base_node + (int)(v >> 17);
                int slot = atomicAdd(&deg[d], 1);
                if (slot < CAP)
                    ell[(((size_t)(slot >> 4) * n_nodes + d) << 4) + (slot & 15)] = sv;
            }
        }
    }
    if (blockIdx.x == 0) {  // drain (expected-empty) overflow list
        int n = *ovf_cnt; n = (n < OVF_CAP) ? n : OVF_CAP;
        for (int i = threadIdx.x; i < n; i += 256) {
            int sv = ovf[2 * i], d = ovf[2 * i + 1];
            int slot = atomicAdd(&deg[d], 1);
            if (slot < CAP)
                ell[(((size_t)(slot >> 4) * n_nodes + d) << 4) + (slot & 15)] = sv;
        }
    }
}

// ---- t[node][o] = sum_f h[node][f] * W[o][f] ----
template <int OUT, int NPN>
__global__ __launch_bounds__(256) void transform_k(const float* __restrict__ h,
                                                   const float* __restrict__ W,
                                                   float* __restrict__ t, int n_nodes) {
    const int lane = threadIdx.x & 63;
    const int wave = (blockIdx.x << 2) | (threadIdx.x >> 6);
    const int wrow = (OUT == 64) ? lane : ((lane < OUT) ? lane : 0);
    float4 wreg[16];
    const float4* W4 = (const float4*)(W + wrow * N_FEAT);
#pragma unroll
    for (int k = 0; k < 16; ++k) wreg[k] = W4[k];
    const float* wf = (const float*)wreg;
    const bool has = (OUT == 64) || (lane < OUT);

    const int node0 = wave * NPN;
    for (int k = 0; k < NPN; ++k) {
        const int node = node0 + k;
        if (node >= n_nodes) return;  // wave-uniform
        const float hv = h[(size_t)node * N_FEAT + lane];
        float acc = 0.f;
#pragma unroll
        for (int f = 0; f < 64; ++f) {
            float bcast = __int_as_float(__builtin_amdgcn_readlane(__float_as_int(hv), f));
            acc = fmaf(bcast, wf[f], acc);
        }
        if (has) t[(size_t)node * OUT + lane] = acc;
    }
}

// ---- out = relu?((seg(t)+t)*inv + b), 64-wide, 2-deep node pipeline ----
// ELL plane layout: slot s of node d at ell[((s>>4)*N + d)*16 + (s&15)].
template <bool RELU, int NPW>
__global__ __launch_bounds__(256) void agg64_k(const float* __restrict__ t,
                                               const float* __restrict__ bias,
                                               const int* __restrict__ deg,
                                               const int* __restrict__ ell,
                                               float* __restrict__ out, int n_nodes) {
    const int lane = threadIdx.x & 63;
    const int wave = (blockIdx.x << 2) | (threadIdx.x >> 6);
    const int g = lane >> 4;
    const int q = lane & 15;
    const float4* t4 = (const float4*)t;
    const int4* ell4 = (const int4*)ell;
    const float4 bq = ((const float4*)bias)[q];
    const int node0 = wave * NPW;
    if (node0 >= n_nodes) return;
    const int e0 = g * 4;

    if (node0 + NPW <= n_nodes) {
        int dg[NPW];
#pragma unroll
        for (int k = 0; k < NPW; ++k) dg[k] = deg[node0 + k];
        float4 self[NPW];
#pragma unroll
        for (int k = 0; k < NPW; ++k) self[k] = t4[(size_t)(node0 + k) * 16 + q];

        int4 idxb[2];
        float4 vb[2][4];
        idxb[0] = ell4[(size_t)node0 * 4 + g];           // plane 0
        {
            int4 ix = idxb[0]; const int d = dg[0];
            vb[0][0] = t4[(size_t)((e0 + 0 < d) ? ix.x : 0) * 16 + q];
            vb[0][1] = t4[(size_t)((e0 + 1 < d) ? ix.y : 0) * 16 + q];
            vb[0][2] = t4[(size_t)((e0 + 2 < d) ? ix.z : 0) * 16 + q];
            vb[0][3] = t4[(size_t)((e0 + 3 < d) ? ix.w : 0) * 16 + q];
        }
        if (NPW > 1) idxb[1] = ell4[(size_t)(node0 + 1) * 4 + g];

#pragma unroll
        for (int k = 0; k < NPW; ++k) {
            if (k + 1 < NPW) {  // issue gathers for node k+1
                int4 ix = idxb[(k + 1) & 1]; const int d = dg[k + 1];
                float4* v = vb[(k + 1) & 1];
                v[0] = t4[(size_t)((e0 + 0 < d) ? ix.x : 0) * 16 + q];
                v[1] = t4[(size_t)((e0 + 1 < d) ? ix.y : 0) * 16 + q];
                v[2] = t4[(size_t)((e0 + 2 < d) ? ix.z : 0) * 16 + q];
                v[3] = t4[(size_t)((e0 + 3 < d) ? ix.w : 0) * 16 + q];
            }
            if (k + 2 < NPW) idxb[k & 1] = ell4[(size_t)(node0 + k + 2) * 4 + g];

            // consume node k
            const int node = node0 + k;
            const int d = dg[k];
            const float4* v = vb[k & 1];
            const float m0 = (e0 + 0 < d) ? 1.f : 0.f;
            const float m1 = (e0 + 1 < d) ? 1.f : 0.f;
            const float m2 = (e0 + 2 < d) ? 1.f : 0.f;
            const float m3 = (e0 + 3 < d) ? 1.f : 0.f;
            float4 acc;
            acc.x = m0 * v[0].x; acc.y = m0 * v[0].y; acc.z = m0 * v[0].z; acc.w = m0 * v[0].w;
            acc.x = fmaf(m1, v[1].x, acc.x); acc.y = fmaf(m1, v[1].y, acc.y);
            acc.z = fmaf(m1, v[1].z, acc.z); acc.w = fmaf(m1, v[1].w, acc.w);
            acc.x = fmaf(m2, v[2].x, acc.x); acc.y = fmaf(m2, v[2].y, acc.y);
            acc.z = fmaf(m2, v[2].z, acc.z); acc.w = fmaf(m2, v[2].w, acc.w);
            acc.x = fmaf(m3, v[3].x, acc.x); acc.y = fmaf(m3, v[3].y, acc.y);
            acc.z = fmaf(m3, v[3].z, acc.z); acc.w = fmaf(m3, v[3].w, acc.w);

            const int dcap = (d < CAP) ? d : CAP;
            for (int u = 1; u * 16 < dcap; ++u) {  // tail: planes 1..3 (deg > 16)
                int4 ix = ell4[((size_t)u * n_nodes + node) * 4 + g];
                const int eb = u * 16 + g * 4;
                int i0 = (eb + 0 < d) ? ix.x : 0;
                int i1 = (eb + 1 < d) ? ix.y : 0;
                int i2 = (eb + 2 < d) ? ix.z : 0;
                int i3 = (eb + 3 < d) ? ix.w : 0;
                float n0 = (eb + 0 < d) ? 1.f : 0.f;
                float n1 = (eb + 1 < d) ? 1.f : 0.f;
                float n2 = (eb + 2 < d) ? 1.f : 0.f;
                float n3 = (eb + 3 < d) ? 1.f : 0.f;
                float4 w0 = t4[(size_t)i0 * 16 + q];
                float4 w1 = t4[(size_t)i1 * 16 + q];
                float4 w2 = t4[(size_t)i2 * 16 + q];
                float4 w3 = t4[(size_t)i3 * 16 + q];
                acc.x = fmaf(n0, w0.x, acc.x); acc.y = fmaf(n0, w0.y, acc.y);
                acc.z = fmaf(n0, w0.z, acc.z); acc.w = fmaf(n0, w0.w, acc.w);
                acc.x = fmaf(n1, w1.x, acc.x); acc.y = fmaf(n1, w1.y, acc.y);
                acc.z = fmaf(n1, w1.z, acc.z); acc.w = fmaf(n1, w1.w, acc.w);
                acc.x = fmaf(n2, w2.x, acc.x); acc.y = fmaf(n2, w2.y, acc.y);
                acc.z = fmaf(n2, w2.z, acc.z); acc.w = fmaf(n2, w2.w, acc.w);
                acc.x = fmaf(n3, w3.x, acc.x); acc.y = fmaf(n3, w3.y, acc.y);
                acc.z = fmaf(n3, w3.z, acc.z); acc.w = fmaf(n3, w3.w, acc.w);
            }

            acc.x += __shfl_xor(acc.x, 16, 64); acc.y += __shfl_xor(acc.y, 16, 64);
            acc.z += __shfl_xor(acc.z, 16, 64); acc.w += __shfl_xor(acc.w, 16, 64);
            acc.x += __shfl_xor(acc.x, 32, 64); acc.y += __shfl_xor(acc.y, 32, 64);
            acc.z += __shfl_xor(acc.z, 32, 64); acc.w += __shfl_xor(acc.w, 32, 64);

            const float invv = 1.0f / (float)(d + 1);
            float4 r;
            r.x = (acc.x + self[k].x) * invv + bq.x;
            r.y = (acc.y + self[k].y) * invv + bq.y;
            r.z = (acc.z + self[k].z) * invv + bq.z;
            r.w = (acc.w + self[k].w) * invv + bq.w;
            if (RELU) {
                r.x = fmaxf(r.x, 0.f); r.y = fmaxf(r.y, 0.f);
                r.z = fmaxf(r.z, 0.f); r.w = fmaxf(r.w, 0.f);
            }
            if (g == 0) ((float4*)out)[(size_t)node * 16 + q] = r;
        }
    } else {
        // generic tail path (not taken for N=100000)
        for (int k = 0; k < NPW; ++k) {
            const int node = node0 + k;
            if (node >= n_nodes) return;
            const int d = deg[node];
            const int dcap = (d < CAP) ? d : CAP;
            float4 acc = make_float4(0.f, 0.f, 0.f, 0.f);
            for (int u = 0; u * 16 < dcap; ++u) {
                int4 ix = ell4[((size_t)u * n_nodes + node) * 4 + g];
                const int eb = u * 16 + g * 4;
                for (int j = 0; j < 4; ++j) {
                    int ii = (j == 0) ? ix.x : (j == 1) ? ix.y : (j == 2) ? ix.z : ix.w;
                    float mm = (eb + j < d) ? 1.f : 0.f;
                    if (eb + j >= d) ii = 0;
                    float4 vv = t4[(size_t)ii * 16 + q];
                    acc.x = fmaf(mm, vv.x, acc.x); acc.y = fmaf(mm, vv.y, acc.y);
                    acc.z = fmaf(mm, vv.z, acc.z); acc.w = fmaf(mm, vv.w, acc.w);
                }
            }
            acc.x += __shfl_xor(acc.x, 16, 64); acc.y += __shfl_xor(acc.y, 16, 64);
            acc.z += __shfl_xor(acc.z, 16, 64); acc.w += __shfl_xor(acc.w, 16, 64);
            acc.x += __shfl_xor(acc.x, 32, 64); acc.y += __shfl_xor(acc.y, 32, 64);
            acc.z += __shfl_xor(acc.z, 32, 64); acc.w += __shfl_xor(acc.w, 32, 64);
            float4 self = t4[(size_t)node * 16 + q];
            const float invv = 1.0f / (float)(d + 1);
            float4 r;
            r.x = (acc.x + self.x) * invv + bq.x;
            r.y = (acc.y + self.y) * invv + bq.y;
            r.z = (acc.z + self.z) * invv + bq.z;
            r.w = (acc.w + self.w) * invv + bq.w;
            if (RELU) {
                r.x = fmaxf(r.x, 0.f); r.y = fmaxf(r.y, 0.f);
                r.z = fmaxf(r.z, 0.f); r.w = fmaxf(r.w, 0.f);
            }
            if (g == 0) ((float4*)out)[(size_t)node * 16 + q] = r;
        }
    }
}

// ---- out = (seg(t)+t)*inv + b, 40-wide, 24-edge trips, 2-deep pipeline ----
template <int NPW>
__global__ __launch_bounds__(256) void agg40_k(const float* __restrict__ t,     // [N,40]
                                               const float* __restrict__ bias,  // [40]
                                               const int* __restrict__ deg,
                                               const int* __restrict__ ell,
                                               float* __restrict__ out, int n_nodes) {
    const int lane = threadIdx.x & 63;
    const int wave = (blockIdx.x << 2) | (threadIdx.x >> 6);
    const int g = lane / 10;      // 0..5 active, 6 idle
    const int q = lane - g * 10;  // 0..9
    const bool act = lane < 60;
    const float4* t4 = (const float4*)t;
    const float4 bq = ((const float4*)bias)[q];
    const int node0 = wave * NPW;
    if (node0 >= n_nodes) return;

    int nmax = NPW;
    if (node0 + NPW > n_nodes) nmax = n_nodes - node0;

    int dg[NPW];
#pragma unroll
    for (int k = 0; k < NPW; ++k) dg[k] = deg[node0 + ((k < nmax) ? k : 0)];

    // plane-split ELL address for slot e of node nd
    auto eaddr = [&](int nd, int e) -> size_t {
        return (((size_t)(e >> 4) * n_nodes + nd) << 4) + (e & 15);
    };

    float4 vb[2][4];
    float mb[2][4];
    auto issue = [&](int slot, int k) {
        const int node = node0 + k;
        const int d = dg[k];
        const bool k0 = act && (g + 0 < d);
        const bool k1 = act && (g + 6 < d);
        const bool k2 = act && (g + 12 < d);
        const bool k3 = act && (g + 18 < d);
        int i0 = k0 ? ell[eaddr(node, g + 0)] : 0;
        int i1 = k1 ? ell[eaddr(node, g + 6)] : 0;
        int i2 = k2 ? ell[eaddr(node, g + 12)] : 0;
        int i3 = k3 ? ell[eaddr(node, g + 18)] : 0;
        vb[slot][0] = t4[(size_t)i0 * 10 + q];
        vb[slot][1] = t4[(size_t)i1 * 10 + q];
        vb[slot][2] = t4[(size_t)i2 * 10 + q];
        vb[slot][3] = t4[(size_t)i3 * 10 + q];
        mb[slot][0] = k0 ? 1.f : 0.f; mb[slot][1] = k1 ? 1.f : 0.f;
        mb[slot][2] = k2 ? 1.f : 0.f; mb[slot][3] = k3 ? 1.f : 0.f;
    };

    issue(0, 0);
#pragma unroll
    for (int k = 0; k < NPW; ++k) {
        if (k + 1 < NPW) issue((k + 1) & 1, k + 1);
        if (k >= nmax) break;
        const int node = node0 + k;
        const int d = dg[k];
        const float4* v = vb[k & 1];
        const float* m = mb[k & 1];
        float4 acc;
        acc.x = m[0] * v[0].x; acc.y = m[0] * v[0].y;
        acc.z = m[0] * v[0].z; acc.w = m[0] * v[0].w;
        acc.x = fmaf(m[1], v[1].x, acc.x); acc.y = fmaf(m[1], v[1].y, acc.y);
        acc.z = fmaf(m[1], v[1].z, acc.z); acc.w = fmaf(m[1], v[1].w, acc.w);
        acc.x = fmaf(m[2], v[2].x, acc.x); acc.y = fmaf(m[2], v[2].y, acc.y);
        acc.z = fmaf(m[2], v[2].z, acc.z); acc.w = fmaf(m[2], v[2].w, acc.w);
        acc.x = fmaf(m[3], v[3].x, acc.x); acc.y = fmaf(m[3], v[3].y, acc.y);
        acc.z = fmaf(m[3], v[3].z, acc.z); acc.w = fmaf(m[3], v[3].w, acc.w);

        const int dcap = (d < CAP) ? d : CAP;
        for (int u = 1; u * 24 < dcap; ++u) {  // tail (deg > 24)
            const int eb = u * 24 + g;
            const bool k0 = act && (eb + 0 < d) && (eb + 0 < CAP);
            const bool k1 = act && (eb + 6 < d) && (eb + 6 < CAP);
            const bool k2 = act && (eb + 12 < d) && (eb + 12 < CAP);
            const bool k3 = act && (eb + 18 < d) && (eb + 18 < CAP);
            int i0 = k0 ? ell[eaddr(node, eb + 0)] : 0;
            int i1 = k1 ? ell[eaddr(node, eb + 6)] : 0;
            int i2 = k2 ? ell[eaddr(node, eb + 12)] : 0;
            int i3 = k3 ? ell[eaddr(node, eb + 18)] : 0;
            float n0 = k0 ? 1.f : 0.f;
            float n1 = k1 ? 1.f : 0.f;
            float n2 = k2 ? 1.f : 0.f;
            float n3 = k3 ? 1.f : 0.f;
            float4 w0 = t4[(size_t)i0 * 10 + q];
            float4 w1 = t4[(size_t)i1 * 10 + q];
            float4 w2 = t4[(size_t)i2 * 10 + q];
            float4 w3 = t4[(size_t)i3 * 10 + q];
            acc.x = fmaf(n0, w0.x, acc.x); acc.y = fmaf(n0, w0.y, acc.y);
            acc.z = fmaf(n0, w0.z, acc.z); acc.w = fmaf(n0, w0.w, acc.w);
            acc.x = fmaf(n1, w1.x, acc.x); acc.y = fmaf(n1, w1.y, acc.y);
            acc.z = fmaf(n1, w1.z, acc.z); acc.w = fmaf(n1, w1.w, acc.w);
            acc.x = fmaf(n2, w2.x, acc.x); acc.y = fmaf(n2, w2.y, acc.y);
            acc.z = fmaf(n2, w2.z, acc.z); acc.w = fmaf(n2, w2.w, acc.w);
            acc.x = fmaf(n3, w3.x, acc.x); acc.y = fmaf(n3, w3.y, acc.y);
            acc.z = fmaf(n3, w3.z, acc.z); acc.w = fmaf(n3, w3.w, acc.w);
        }

        // fold 6 groups -> group 0
        acc.x += __shfl(acc.x, lane + 30, 64); acc.y += __shfl(acc.y, lane + 30, 64);
        acc.z += __shfl(acc.z, lane + 30, 64); acc.w += __shfl(acc.w, lane + 30, 64);
        float4 s1, s2;
        s1.x = __shfl(acc.x, lane + 10, 64); s2.x = __shfl(acc.x, lane + 20, 64);
        s1.y = __shfl(acc.y, lane + 10, 64); s2.y = __shfl(acc.y, lane + 20, 64);
        s1.z = __shfl(acc.z, lane + 10, 64); s2.z = __shfl(acc.z, lane + 20, 64);
        s1.w = __shfl(acc.w, lane + 10, 64); s2.w = __shfl(acc.w, lane + 20, 64);
        acc.x += s1.x + s2.x; acc.y += s1.y + s2.y;
        acc.z += s1.z + s2.z; acc.w += s1.w + s2.w;

        const float4 self = t4[(size_t)node * 10 + q];
        const float invv = 1.0f / (float)(d + 1);
        float4 r;
        r.x = (acc.x + self.x) * invv + bq.x;
        r.y = (acc.y + self.y) * invv + bq.y;
        r.z = (acc.z + self.z) * invv + bq.z;
        r.w = (acc.w + self.w) * invv + bq.w;
        if (lane < 10) ((float4*)out)[(size_t)node * 10 + q] = r;
    }
}

extern "C" void kernel_launch(void* const* d_in, const int* in_sizes, int n_in,
                              void* d_out, int out_size, void* d_ws, size_t ws_size,
                              hipStream_t stream) {
    const float* feats = (const float*)d_in[0];
    const int*   src   = (const int*)d_in[1];
    const int*   dst   = (const int*)d_in[2];
    const float* W0    = (const float*)d_in[3];
    const float* b0    = (const float*)d_in[4];
    const float* W1    = (const float*)d_in[5];
    const float* b1    = (const float*)d_in[6];
    const float* W2    = (const float*)d_in[7];
    const float* b2    = (const float*)d_in[8];
    float*       out   = (float*)d_out;

    const int N = in_sizes[0] / N_FEAT;  // 100000
    const int E = in_sizes[1];           // 1600000
    const int PB = (E + 255) / 256;      // phase-1 blocks (6250)
    const int NW = PB * 4;               // phase-1 waves (25000)
    const int BS = (N + 7) / 8;          // nodes per bucket (12500)

    // Workspace (~78 MB). bins aliases Y (bins dead before Y's first write).
    char* p = (char*)d_ws;
    float* X   = (float*)p; p += (size_t)N * N_FEAT * sizeof(float);   // 25.6 MB
    float* Y   = (float*)p; p += (size_t)N * N_FEAT * sizeof(float);   // 25.6 MB
    unsigned int* bins = (unsigned int*)Y;  // 8*NW*CAPW*4 = 19.2 MB <= 25.6
    int*   deg = (int*)p;   p += (size_t)(N + 1) * sizeof(int);        // deg + ovf_cnt
    int*   ovf_cnt = deg + N;
    int*   cnt = (int*)p;   p += (size_t)NW * 8 * sizeof(int);         // 0.8 MB
    int*   ovf = (int*)p;   p += (size_t)OVF_CAP * 2 * sizeof(int);    // 32 KB
    int*   ell = (int*)p;   p += (size_t)N * CAP * sizeof(int);        // 25.6 MB

    hipMemsetAsync(deg, 0, (size_t)(N + 1) * sizeof(int), stream);

    constexpr int NPN = 8;
    constexpr int NPW = 4;
    const int tb = ((N + NPN - 1) / NPN + 3) / 4;
    const int ab = ((N + NPW - 1) / NPW + 3) / 4;

    bin_edges<<<PB, 256, 0, stream>>>(src, dst, bins, cnt, ovf, ovf_cnt, E, BS, NW);
    transform_k<64, NPN><<<tb, 256, 0, stream>>>(feats, W0, X, N);
    fill_from_bins<<<2048, 256, 0, stream>>>(bins, cnt, ovf, ovf_cnt, deg, ell, NW, BS, N);
    agg64_k<true, NPW><<<ab, 256, 0, stream>>>(X, b0, deg, ell, Y, N);
    transform_k<64, NPN><<<tb, 256, 0, stream>>>(Y, W1, X, N);
    agg64_k<true, NPW><<<ab, 256, 0, stream>>>(X, b1, deg, ell, Y, N);
    transform_k<40, NPN><<<tb, 256, 0, stream>>>(Y, W2, X, N);
    agg40_k<NPW><<<ab, 256, 0, stream>>>(X, b2, deg, ell, out, N);
}

// Round 7
// 441.647 us; speedup vs baseline: 1.0372x; 1.0372x over previous
//
#include <hip/hip_runtime.h>
#include <hip/hip_bf16.h>

// GraphSAGE (GCN-aggregator) — 3 layers, fp32.
// Structure: transform-then-aggregate ((seg(t)+t)*inv + b, t = h@W^T).
// R7 changes:
//  (a) packed cnt64: bin_edges emits one uint64 (8x8-bit counts) per wave;
//      fill reads it as one dense line. R6's cnt[sg*8+c] reads fetched
//      ~12.8MB of 16x-amplified lines through L2, thrashing dirty ELL
//      lines (FETCH 13.4MB, WRITE 65MB on fill).
//  (b) fusion: prep = bin_edges || transform0 (independent, block-split);
//      next-layer transform folded into agg epilogue (readlane-GEMM is
//      free under gather latency — R4 evidence). 9 -> 6 dispatches.
// fp32 throughout (bf16 would exceed the 7.1e-4 absmax threshold).

#define N_FEAT 64
#define CAP 64    // ELL slots per node (4 planes of 16)
#define CAPW 24   // bin slots per (bucket, wave)
#define OVF_CAP 4096

__device__ __forceinline__ float rl(float v, int l) {
    return __int_as_float(__builtin_amdgcn_readlane(__float_as_int(v), l));
}

// ---- bin_edges body: bin edges by dst bucket (atomic-free, packed cnt) ----
__device__ __forceinline__ void bin_body(const int* __restrict__ src,
                                         const int* __restrict__ dst,
                                         unsigned int* __restrict__ bins,  // [8, nw, CAPW]
                                         unsigned long long* __restrict__ cnt64,  // [nw]
                                         int* __restrict__ ovf, int* __restrict__ ovf_cnt,
                                         int n_edges, int bsize, int nw, int bid) {
    const int e = bid * 256 + threadIdx.x;
    const int lane = threadIdx.x & 63;
    const int wid = (bid << 2) | (threadIdx.x >> 6);
    const bool valid = e < n_edges;
    int s = 0, d = 0;
    if (valid) { s = src[e]; d = dst[e]; }
    const unsigned int bucket = valid ? ((unsigned int)d / (unsigned int)bsize) : 8u;
    const unsigned int local = valid ? (unsigned int)(d - (int)bucket * bsize) : 0u;
    const unsigned int pack = (local << 17) | (unsigned int)s;

    int mycnt = 0;
    for (int c = 0; c < 8; ++c) {
        unsigned long long m = __ballot(valid && bucket == (unsigned int)c);
        int cc = __popcll(m);
        if (lane == c) mycnt = (cc < CAPW) ? cc : CAPW;
        if (valid && bucket == (unsigned int)c) {
            int pfx = __popcll(m & ((1ull << lane) - 1ull));
            if (pfx < CAPW) {
                __builtin_nontemporal_store(pack, &bins[((size_t)c * nw + wid) * CAPW + pfx]);
            } else {
                int p = atomicAdd(ovf_cnt, 1);
                if (p < OVF_CAP) { ovf[2 * p] = s; ovf[2 * p + 1] = d; }
            }
        }
    }
    unsigned long long packed = 0;
#pragma unroll
    for (int c = 0; c < 8; ++c) {
        int v = __builtin_amdgcn_readlane(mycnt, c);
        packed |= ((unsigned long long)(v & 0xFF)) << (8 * c);
    }
    if (lane == 0) cnt64[wid] = packed;
}

// ---- transform body: t[node][o] = sum_f h[node][f] * W[o][f]  (OUT=64) ----
__device__ __forceinline__ void transform64_body(const float* __restrict__ h,
                                                 const float* __restrict__ W,
                                                 float* __restrict__ t, int n_nodes, int bid) {
    const int lane = threadIdx.x & 63;
    const int wave = (bid << 2) | (threadIdx.x >> 6);
    float4 wreg[16];
    const float4* W4 = (const float4*)(W + lane * N_FEAT);
#pragma unroll
    for (int k = 0; k < 16; ++k) wreg[k] = W4[k];
    const float* wf = (const float*)wreg;

    const int node0 = wave * 8;
    for (int k = 0; k < 8; ++k) {
        const int node = node0 + k;
        if (node >= n_nodes) return;  // wave-uniform
        const float hv = h[(size_t)node * N_FEAT + lane];
        float acc = 0.f;
#pragma unroll
        for (int f = 0; f < 64; ++f) acc = fmaf(rl(hv, f), wf[f], acc);
        t[(size_t)node * N_FEAT + lane] = acc;
    }
}

// ---- fused: bin_edges (blocks [0,PB)) || transform0 (blocks [PB, PB+tb)) ----
__global__ __launch_bounds__(256) void prep(const int* __restrict__ src,
                                            const int* __restrict__ dst,
                                            unsigned int* __restrict__ bins,
                                            unsigned long long* __restrict__ cnt64,
                                            int* __restrict__ ovf, int* __restrict__ ovf_cnt,
                                            int n_edges, int bsize, int nw,
                                            const float* __restrict__ feats,
                                            const float* __restrict__ W0,
                                            float* __restrict__ t0, int n_nodes, int PB) {
    const int b = (int)blockIdx.x;
    if (b < PB)
        bin_body(src, dst, bins, cnt64, ovf, ovf_cnt, n_edges, bsize, nw, b);
    else
        transform64_body(feats, W0, t0, n_nodes, b - PB);
}

// ---- phase 2: scatter bins into plane-split ELL; bucket = blockIdx%8 ----
__global__ __launch_bounds__(256) void fill_from_bins(const unsigned int* __restrict__ bins,
                                                      const unsigned long long* __restrict__ cnt64,
                                                      const int* __restrict__ ovf,
                                                      const int* __restrict__ ovf_cnt,
                                                      int* __restrict__ deg,
                                                      int* __restrict__ ell,
                                                      int nw, int bsize, int n_nodes) {
    const int lane = threadIdx.x & 63;
    const int w = threadIdx.x >> 6;
    const int c = blockIdx.x & 7;          // bucket -> XCD (round-robin dispatch)
    const int jb = blockIdx.x >> 3;
    const int base_node = c * bsize;
    const int sub = lane >> 3;             // 8 sub-segments per wave
    const int rr = lane & 7;               // record id within tier
    const int wave_in_bucket = jb * 4 + w;
    const int nwaves = (gridDim.x >> 3) * 4;
    const int shift = 8 * c;

    for (int s0 = wave_in_bucket * 8; s0 < nw; s0 += nwaves * 8) {
        const int sg = s0 + sub;
        unsigned long long word = (sg < nw) ? cnt64[sg] : 0ull;  // one 64B line/iter
        const int n = (int)((word >> shift) & 0xFFull);
#pragma unroll
        for (int t = 0; t < 3; ++t) {          // tiers: records 0-7, 8-15, 16-23
            const int rec = t * 8 + rr;
            const bool act = rec < n;
            unsigned long long bm = __ballot(act);
            if (!bm) break;                    // wave-uniform early out
            if (act) {
                unsigned int v = __builtin_nontemporal_load(
                    &bins[((size_t)c * nw + sg) * CAPW + rec]);
                int sv = (int)(v & 0x1FFFFu);
                int d = base_node + (int)(v >> 17);
                int slot = atomicAdd(&deg[d], 1);
                if (slot < CAP)
                    ell[(((size_t)(slot >> 4) * n_nodes + d) << 4) + (slot & 15)] = sv;
            }
        }
    }
    if (blockIdx.x == 0) {  // drain (expected-empty) overflow list
        int n = *ovf_cnt; n = (n < OVF_CAP) ? n : OVF_CAP;
        for (int i = threadIdx.x; i < n; i += 256) {
            int sv = ovf[2 * i], d = ovf[2 * i + 1];
            int slot = atomicAdd(&deg[d], 1);
            if (slot < CAP)
                ell[(((size_t)(slot >> 4) * n_nodes + d) << 4) + (slot & 15)] = sv;
        }
    }
}

// ---- fused agg + next transform:
//   h = relu((seg(t)+t)*inv + b); t_next[node][o] = sum_f h[f]*Wn[o][f]
// t is 64-wide; ELL plane layout: slot s at ell[((s>>4)*N + d)*16 + (s&15)].
template <int OUTW, int NPW>
__global__ __launch_bounds__(256) void agg_t_k(const float* __restrict__ t,
                                               const float* __restrict__ bias,  // [64]
                                               const float* __restrict__ Wn,    // [OUTW,64]
                                               const int* __restrict__ deg,
                                               const int* __restrict__ ell,
                                               float* __restrict__ tn,          // [N,OUTW]
                                               int n_nodes) {
    const int lane = threadIdx.x & 63;
    const int wave = (blockIdx.x << 2) | (threadIdx.x >> 6);
    const int g = lane >> 4;
    const int q = lane & 15;
    const float4* t4 = (const float4*)t;
    const int4* ell4 = (const int4*)ell;
    const float4 bq = ((const float4*)bias)[q];
    const int wrow = (OUTW == 64) ? lane : ((lane < OUTW) ? lane : 0);
    const float4* Wn4 = (const float4*)(Wn + wrow * N_FEAT);
    float4 wreg[16];
#pragma unroll
    for (int k = 0; k < 16; ++k) wreg[k] = Wn4[k];
    const bool has_out = (OUTW == 64) || (lane < OUTW);

    const int node0 = wave * NPW;
    if (node0 >= n_nodes) return;
    const int e0 = g * 4;

    if (node0 + NPW <= n_nodes) {
        int dg[NPW];
#pragma unroll
        for (int k = 0; k < NPW; ++k) dg[k] = deg[node0 + k];
        float4 self[NPW];
#pragma unroll
        for (int k = 0; k < NPW; ++k) self[k] = t4[(size_t)(node0 + k) * 16 + q];

        int4 idxb[2];
        float4 vb[2][4];
        idxb[0] = ell4[(size_t)node0 * 4 + g];  // plane 0
        {
            int4 ix = idxb[0]; const int d = dg[0];
            vb[0][0] = t4[(size_t)((e0 + 0 < d) ? ix.x : 0) * 16 + q];
            vb[0][1] = t4[(size_t)((e0 + 1 < d) ? ix.y : 0) * 16 + q];
            vb[0][2] = t4[(size_t)((e0 + 2 < d) ? ix.z : 0) * 16 + q];
            vb[0][3] = t4[(size_t)((e0 + 3 < d) ? ix.w : 0) * 16 + q];
        }
        if (NPW > 1) idxb[1] = ell4[(size_t)(node0 + 1) * 4 + g];

#pragma unroll
        for (int k = 0; k < NPW; ++k) {
            if (k + 1 < NPW) {  // issue gathers for node k+1
                int4 ix = idxb[(k + 1) & 1]; const int d = dg[k + 1];
                float4* v = vb[(k + 1) & 1];
                v[0] = t4[(size_t)((e0 + 0 < d) ? ix.x : 0) * 16 + q];
                v[1] = t4[(size_t)((e0 + 1 < d) ? ix.y : 0) * 16 + q];
                v[2] = t4[(size_t)((e0 + 2 < d) ? ix.z : 0) * 16 + q];
                v[3] = t4[(size_t)((e0 + 3 < d) ? ix.w : 0) * 16 + q];
            }
            if (k + 2 < NPW) idxb[k & 1] = ell4[(size_t)(node0 + k + 2) * 4 + g];

            const int node = node0 + k;
            const int d = dg[k];
            const float4* v = vb[k & 1];
            const float m0 = (e0 + 0 < d) ? 1.f : 0.f;
            const float m1 = (e0 + 1 < d) ? 1.f : 0.f;
            const float m2 = (e0 + 2 < d) ? 1.f : 0.f;
            const float m3 = (e0 + 3 < d) ? 1.f : 0.f;
            float4 acc;
            acc.x = m0 * v[0].x; acc.y = m0 * v[0].y; acc.z = m0 * v[0].z; acc.w = m0 * v[0].w;
            acc.x = fmaf(m1, v[1].x, acc.x); acc.y = fmaf(m1, v[1].y, acc.y);
            acc.z = fmaf(m1, v[1].z, acc.z); acc.w = fmaf(m1, v[1].w, acc.w);
            acc.x = fmaf(m2, v[2].x, acc.x); acc.y = fmaf(m2, v[2].y, acc.y);
            acc.z = fmaf(m2, v[2].z, acc.z); acc.w = fmaf(m2, v[2].w, acc.w);
            acc.x = fmaf(m3, v[3].x, acc.x); acc.y = fmaf(m3, v[3].y, acc.y);
            acc.z = fmaf(m3, v[3].z, acc.z); acc.w = fmaf(m3, v[3].w, acc.w);

            const int dcap = (d < CAP) ? d : CAP;
            for (int u = 1; u * 16 < dcap; ++u) {  // tail: planes 1..3 (deg > 16)
                int4 ix = ell4[((size_t)u * n_nodes + node) * 4 + g];
                const int eb = u * 16 + g * 4;
                int i0 = (eb + 0 < d) ? ix.x : 0;
                int i1 = (eb + 1 < d) ? ix.y : 0;
                int i2 = (eb + 2 < d) ? ix.z : 0;
                int i3 = (eb + 3 < d) ? ix.w : 0;
                float n0 = (eb + 0 < d) ? 1.f : 0.f;
                float n1 = (eb + 1 < d) ? 1.f : 0.f;
                float n2 = (eb + 2 < d) ? 1.f : 0.f;
                float n3 = (eb + 3 < d) ? 1.f : 0.f;
                float4 w0 = t4[(size_t)i0 * 16 + q];
                float4 w1 = t4[(size_t)i1 * 16 + q];
                float4 w2 = t4[(size_t)i2 * 16 + q];
                float4 w3 = t4[(size_t)i3 * 16 + q];
                acc.x = fmaf(n0, w0.x, acc.x); acc.y = fmaf(n0, w0.y, acc.y);
                acc.z = fmaf(n0, w0.z, acc.z); acc.w = fmaf(n0, w0.w, acc.w);
                acc.x = fmaf(n1, w1.x, acc.x); acc.y = fmaf(n1, w1.y, acc.y);
                acc.z = fmaf(n1, w1.z, acc.z); acc.w = fmaf(n1, w1.w, acc.w);
                acc.x = fmaf(n2, w2.x, acc.x); acc.y = fmaf(n2, w2.y, acc.y);
                acc.z = fmaf(n2, w2.z, acc.z); acc.w = fmaf(n2, w2.w, acc.w);
                acc.x = fmaf(n3, w3.x, acc.x); acc.y = fmaf(n3, w3.y, acc.y);
                acc.z = fmaf(n3, w3.z, acc.z); acc.w = fmaf(n3, w3.w, acc.w);
            }

            acc.x += __shfl_xor(acc.x, 16, 64); acc.y += __shfl_xor(acc.y, 16, 64);
            acc.z += __shfl_xor(acc.z, 16, 64); acc.w += __shfl_xor(acc.w, 16, 64);
            acc.x += __shfl_xor(acc.x, 32, 64); acc.y += __shfl_xor(acc.y, 32, 64);
            acc.z += __shfl_xor(acc.z, 32, 64); acc.w += __shfl_xor(acc.w, 32, 64);

            // h (relu'd, bias'd) — replicated in all 4 groups per lane
            const float invv = 1.0f / (float)(d + 1);
            float4 r;
            r.x = fmaxf((acc.x + self[k].x) * invv + bq.x, 0.f);
            r.y = fmaxf((acc.y + self[k].y) * invv + bq.y, 0.f);
            r.z = fmaxf((acc.z + self[k].z) * invv + bq.z, 0.f);
            r.w = fmaxf((acc.w + self[k].w) * invv + bq.w, 0.f);

            // t_next[o] = sum_f h[f] * Wn[o][f]; h[4c+j] = readlane(r[j], c)
            float o_acc = 0.f;
#pragma unroll
            for (int c = 0; c < 16; ++c) {
                float4 wv = wreg[c];
                o_acc = fmaf(rl(r.x, c), wv.x, o_acc);
                o_acc = fmaf(rl(r.y, c), wv.y, o_acc);
                o_acc = fmaf(rl(r.z, c), wv.z, o_acc);
                o_acc = fmaf(rl(r.w, c), wv.w, o_acc);
            }
            if (has_out) tn[(size_t)node * OUTW + lane] = o_acc;
        }
    } else {
        // generic tail path (not taken for N=100000, NPW=4)
        for (int k = 0; k < NPW; ++k) {
            const int node = node0 + k;
            if (node >= n_nodes) return;
            const int d = deg[node];
            const int dcap = (d < CAP) ? d : CAP;
            float4 acc = make_float4(0.f, 0.f, 0.f, 0.f);
            for (int u = 0; u * 16 < dcap; ++u) {
                int4 ix = ell4[((size_t)u * n_nodes + node) * 4 + g];
                const int eb = u * 16 + g * 4;
                for (int j = 0; j < 4; ++j) {
                    int ii = (j == 0) ? ix.x : (j == 1) ? ix.y : (j == 2) ? ix.z : ix.w;
                    float mm = (eb + j < d) ? 1.f : 0.f;
                    if (eb + j >= d) ii = 0;
                    float4 vv = t4[(size_t)ii * 16 + q];
                    acc.x = fmaf(mm, vv.x, acc.x); acc.y = fmaf(mm, vv.y, acc.y);
                    acc.z = fmaf(mm, vv.z, acc.z); acc.w = fmaf(mm, vv.w, acc.w);
                }
            }
            acc.x += __shfl_xor(acc.x, 16, 64); acc.y += __shfl_xor(acc.y, 16, 64);
            acc.z += __shfl_xor(acc.z, 16, 64); acc.w += __shfl_xor(acc.w, 16, 64);
            acc.x += __shfl_xor(acc.x, 32, 64); acc.y += __shfl_xor(acc.y, 32, 64);
            acc.z += __shfl_xor(acc.z, 32, 64); acc.w += __shfl_xor(acc.w, 32, 64);
            float4 self = t4[(size_t)node * 16 + q];
            const float invv = 1.0f / (float)(d + 1);
            float4 r;
            r.x = fmaxf((acc.x + self.x) * invv + bq.x, 0.f);
            r.y = fmaxf((acc.y + self.y) * invv + bq.y, 0.f);
            r.z = fmaxf((acc.z + self.z) * invv + bq.z, 0.f);
            r.w = fmaxf((acc.w + self.w) * invv + bq.w, 0.f);
            float o_acc = 0.f;
#pragma unroll
            for (int c = 0; c < 16; ++c) {
                float4 wv = wreg[c];
                o_acc = fmaf(rl(r.x, c), wv.x, o_acc);
                o_acc = fmaf(rl(r.y, c), wv.y, o_acc);
                o_acc = fmaf(rl(r.z, c), wv.z, o_acc);
                o_acc = fmaf(rl(r.w, c), wv.w, o_acc);
            }
            if (has_out) tn[(size_t)node * OUTW + lane] = o_acc;
        }
    }
}

// ---- final: out = (seg(t)+t)*inv + b, 40-wide, 2-deep pipeline ----
template <int NPW>
__global__ __launch_bounds__(256) void agg40_k(const float* __restrict__ t,     // [N,40]
                                               const float* __restrict__ bias,  // [40]
                                               const int* __restrict__ deg,
                                               const int* __restrict__ ell,
                                               float* __restrict__ out, int n_nodes) {
    const int lane = threadIdx.x & 63;
    const int wave = (blockIdx.x << 2) | (threadIdx.x >> 6);
    const int g = lane / 10;      // 0..5 active, 6 idle
    const int q = lane - g * 10;  // 0..9
    const bool act = lane < 60;
    const float4* t4 = (const float4*)t;
    const float4 bq = ((const float4*)bias)[q];
    const int node0 = wave * NPW;
    if (node0 >= n_nodes) return;

    int nmax = NPW;
    if (node0 + NPW > n_nodes) nmax = n_nodes - node0;

    int dg[NPW];
#pragma unroll
    for (int k = 0; k < NPW; ++k) dg[k] = deg[node0 + ((k < nmax) ? k : 0)];

    auto eaddr = [&](int nd, int e) -> size_t {
        return (((size_t)(e >> 4) * n_nodes + nd) << 4) + (e & 15);
    };

    float4 vb[2][4];
    float mb[2][4];
    auto issue = [&](int slot, int k) {
        const int node = node0 + k;
        const int d = dg[k];
        const bool k0 = act && (g + 0 < d);
        const bool k1 = act && (g + 6 < d);
        const bool k2 = act && (g + 12 < d);
        const bool k3 = act && (g + 18 < d);
        int i0 = k0 ? ell[eaddr(node, g + 0)] : 0;
        int i1 = k1 ? ell[eaddr(node, g + 6)] : 0;
        int i2 = k2 ? ell[eaddr(node, g + 12)] : 0;
        int i3 = k3 ? ell[eaddr(node, g + 18)] : 0;
        vb[slot][0] = t4[(size_t)i0 * 10 + q];
        vb[slot][1] = t4[(size_t)i1 * 10 + q];
        vb[slot][2] = t4[(size_t)i2 * 10 + q];
        vb[slot][3] = t4[(size_t)i3 * 10 + q];
        mb[slot][0] = k0 ? 1.f : 0.f; mb[slot][1] = k1 ? 1.f : 0.f;
        mb[slot][2] = k2 ? 1.f : 0.f; mb[slot][3] = k3 ? 1.f : 0.f;
    };

    issue(0, 0);
#pragma unroll
    for (int k = 0; k < NPW; ++k) {
        if (k + 1 < NPW) issue((k + 1) & 1, k + 1);
        if (k >= nmax) break;
        const int node = node0 + k;
        const int d = dg[k];
        const float4* v = vb[k & 1];
        const float* m = mb[k & 1];
        float4 acc;
        acc.x = m[0] * v[0].x; acc.y = m[0] * v[0].y;
        acc.z = m[0] * v[0].z; acc.w = m[0] * v[0].w;
        acc.x = fmaf(m[1], v[1].x, acc.x); acc.y = fmaf(m[1], v[1].y, acc.y);
        acc.z = fmaf(m[1], v[1].z, acc.z); acc.w = fmaf(m[1], v[1].w, acc.w);
        acc.x = fmaf(m[2], v[2].x, acc.x); acc.y = fmaf(m[2], v[2].y, acc.y);
        acc.z = fmaf(m[2], v[2].z, acc.z); acc.w = fmaf(m[2], v[2].w, acc.w);
        acc.x = fmaf(m[3], v[3].x, acc.x); acc.y = fmaf(m[3], v[3].y, acc.y);
        acc.z = fmaf(m[3], v[3].z, acc.z); acc.w = fmaf(m[3], v[3].w, acc.w);

        const int dcap = (d < CAP) ? d : CAP;
        for (int u = 1; u * 24 < dcap; ++u) {  // tail (deg > 24)
            const int eb = u * 24 + g;
            const bool k0 = act && (eb + 0 < d) && (eb + 0 < CAP);
            const bool k1 = act && (eb + 6 < d) && (eb + 6 < CAP);
            const bool k2 = act && (eb + 12 < d) && (eb + 12 < CAP);
            const bool k3 = act && (eb + 18 < d) && (eb + 18 < CAP);
            int i0 = k0 ? ell[eaddr(node, eb + 0)] : 0;
            int i1 = k1 ? ell[eaddr(node, eb + 6)] : 0;
            int i2 = k2 ? ell[eaddr(node, eb + 12)] : 0;
            int i3 = k3 ? ell[eaddr(node, eb + 18)] : 0;
            float n0 = k0 ? 1.f : 0.f;
            float n1 = k1 ? 1.f : 0.f;
            float n2 = k2 ? 1.f : 0.f;
            float n3 = k3 ? 1.f : 0.f;
            float4 w0 = t4[(size_t)i0 * 10 + q];
            float4 w1 = t4[(size_t)i1 * 10 + q];
            float4 w2 = t4[(size_t)i2 * 10 + q];
            float4 w3 = t4[(size_t)i3 * 10 + q];
            acc.x = fmaf(n0, w0.x, acc.x); acc.y = fmaf(n0, w0.y, acc.y);
            acc.z = fmaf(n0, w0.z, acc.z); acc.w = fmaf(n0, w0.w, acc.w);
            acc.x = fmaf(n1, w1.x, acc.x); acc.y = fmaf(n1, w1.y, acc.y);
            acc.z = fmaf(n1, w1.z, acc.z); acc.w = fmaf(n1, w1.w, acc.w);
            acc.x = fmaf(n2, w2.x, acc.x); acc.y = fmaf(n2, w2.y, acc.y);
            acc.z = fmaf(n2, w2.z, acc.z); acc.w = fmaf(n2, w2.w, acc.w);
            acc.x = fmaf(n3, w3.x, acc.x); acc.y = fmaf(n3, w3.y, acc.y);
            acc.z = fmaf(n3, w3.z, acc.z); acc.w = fmaf(n3, w3.w, acc.w);
        }

        // fold 6 groups -> group 0
        acc.x += __shfl(acc.x, lane + 30, 64); acc.y += __shfl(acc.y, lane + 30, 64);
        acc.z += __shfl(acc.z, lane + 30, 64); acc.w += __shfl(acc.w, lane + 30, 64);
        float4 s1, s2;
        s1.x = __shfl(acc.x, lane + 10, 64); s2.x = __shfl(acc.x, lane + 20, 64);
        s1.y = __shfl(acc.y, lane + 10, 64); s2.y = __shfl(acc.y, lane + 20, 64);
        s1.z = __shfl(acc.z, lane + 10, 64); s2.z = __shfl(acc.z, lane + 20, 64);
        s1.w = __shfl(acc.w, lane + 10, 64); s2.w = __shfl(acc.w, lane + 20, 64);
        acc.x += s1.x + s2.x; acc.y += s1.y + s2.y;
        acc.z += s1.z + s2.z; acc.w += s1.w + s2.w;

        const float4 self = t4[(size_t)node * 10 + q];
        const float invv = 1.0f / (float)(d + 1);
        float4 r;
        r.x = (acc.x + self.x) * invv + bq.x;
        r.y = (acc.y + self.y) * invv + bq.y;
        r.z = (acc.z + self.z) * invv + bq.z;
        r.w = (acc.w + self.w) * invv + bq.w;
        if (lane < 10) ((float4*)out)[(size_t)node * 10 + q] = r;
    }
}

extern "C" void kernel_launch(void* const* d_in, const int* in_sizes, int n_in,
                              void* d_out, int out_size, void* d_ws, size_t ws_size,
                              hipStream_t stream) {
    const float* feats = (const float*)d_in[0];
    const int*   src   = (const int*)d_in[1];
    const int*   dst   = (const int*)d_in[2];
    const float* W0    = (const float*)d_in[3];
    const float* b0    = (const float*)d_in[4];
    const float* W1    = (const float*)d_in[5];
    const float* b1    = (const float*)d_in[6];
    const float* W2    = (const float*)d_in[7];
    const float* b2    = (const float*)d_in[8];
    float*       out   = (float*)d_out;

    const int N = in_sizes[0] / N_FEAT;  // 100000
    const int E = in_sizes[1];           // 1600000
    const int PB = (E + 255) / 256;      // bin blocks (6250)
    const int NW = PB * 4;               // bin waves (25000)
    const int BS = (N + 7) / 8;          // nodes per bucket (12500)

    // Workspace (~78 MB). bins aliases Y (bins dead before Y's first write).
    char* p = (char*)d_ws;
    float* X   = (float*)p; p += (size_t)N * N_FEAT * sizeof(float);   // 25.6 MB
    float* Y   = (float*)p; p += (size_t)N * N_FEAT * sizeof(float);   // 25.6 MB
    unsigned int* bins = (unsigned int*)Y;  // 8*NW*CAPW*4 = 19.2 MB <= 25.6
    int*   deg = (int*)p;   p += (size_t)(N + 1) * sizeof(int);        // deg + ovf_cnt
    int*   ovf_cnt = deg + N;
    int*   ovf = (int*)p;   p += (size_t)OVF_CAP * 2 * sizeof(int);    // 32 KB
    unsigned long long* cnt64 = (unsigned long long*)p;
    p += (size_t)NW * sizeof(unsigned long long);                      // 200 KB
    int*   ell = (int*)p;   p += (size_t)N * CAP * sizeof(int);        // 25.6 MB

    hipMemsetAsync(deg, 0, (size_t)(N + 1) * sizeof(int), stream);

    constexpr int NPW = 4;
    const int tb = ((N + 7) / 8 + 3) / 4;                 // transform blocks (3125)
    const int ab = ((N + NPW - 1) / NPW + 3) / 4;         // agg blocks (6250)

    // bin_edges || t0 = feats @ W0^T  (independent)
    prep<<<PB + tb, 256, 0, stream>>>(src, dst, bins, cnt64, ovf, ovf_cnt,
                                      E, BS, NW, feats, W0, X, N, PB);
    fill_from_bins<<<2048, 256, 0, stream>>>(bins, cnt64, ovf, ovf_cnt, deg, ell, NW, BS, N);
    // t1 = relu((seg(t0)+t0)*inv + b0) @ W1^T
    agg_t_k<64, NPW><<<ab, 256, 0, stream>>>(X, b0, W1, deg, ell, Y, N);
    // t2 = relu((seg(t1)+t1)*inv + b1) @ W2^T   (40-wide)
    agg_t_k<40, NPW><<<ab, 256, 0, stream>>>(Y, b1, W2, deg, ell, X, N);
    // out = (seg(t2)+t2)*inv + b2
    agg40_k<NPW><<<ab, 256, 0, stream>>>(X, b2, deg, ell, out, N);
}